// Round 7
// baseline (504.203 us; speedup 1.0000x reference)
//
#include <hip/hip_runtime.h>
#include <hip/hip_bf16.h>
#include <math.h>

#define N_PTS 20000
#define C_IN 128
#define C_OUT 64
#define M_PTS (N_PTS*8)
#define EPS 1e-5f

typedef __attribute__((ext_vector_type(8))) short short8;
typedef __attribute__((ext_vector_type(4))) float float4v;

__device__ __forceinline__ ushort f2bf(float f){
    unsigned int i = __float_as_uint(f);
    unsigned int r = i + 0x7fffu + ((i >> 16) & 1u);
    return (ushort)(r >> 16);
}
__device__ __forceinline__ float bf2f(ushort u){ return __uint_as_float(((unsigned int)u) << 16); }
__device__ __forceinline__ float silu(float z){ return z / (1.f + expf(-z)); }

struct Frag { short8 a0, a1, b0, b1, b2, b3; };

// stats layout (fp32, ws): [0..31] gn1 group sum, [32..63] gn1 group sumsq,
//                          [64..127] gn2 ch sum, [128..191] gn2 ch sumsq

// ================= K1: Wsum1 prep + Wt2 prep + pg_init + gn1_partial =================
// blocks: [0,2048) Wsum1, [2048,2480) Wt2, [2480,2608) pg_init, [2608,3120) gn1
__global__ void __launch_bounds__(256) prep_kernel(
    const float* __restrict__ W1, const float* __restrict__ W2,
    ushort* __restrict__ Wsum1, ushort* __restrict__ Wt2,
    int* __restrict__ pg, ushort* __restrict__ h, ushort* __restrict__ h2,
    const float* __restrict__ x, float* __restrict__ stats)
{
    const int b = blockIdx.x, tid = threadIdx.x;
    if (b < 2048){
        // Wsum1[(((o*8+qi)*4+kb)*4+nb)*512 + l*8 + j] = sum of W1 taps mapping to parent-offset q
        int idx = b * 256 + tid;
        int j = idx & 7, lq = (idx >> 3) & 63, nb = (idx >> 9) & 3, kb = (idx >> 11) & 3, tq = idx >> 13;
        int o = tq >> 3, qi = tq & 7;
        int bx = (o >> 2) & 1, by = (o >> 1) & 1, bz = o & 1;
        int qx = (bx ? ((qi >> 2) & 1) : ((qi >> 2) & 1) - 1);
        int qy = (by ? ((qi >> 1) & 1) : ((qi >> 1) & 1) - 1);
        int qz = (bz ? (qi & 1) : (qi & 1) - 1);
        int ci = kb * 32 + (lq >> 4) * 8 + j, co = nb * 16 + (lq & 15);
        float sum = 0.f;
#pragma unroll
        for (int dx = -1; dx <= 1; dx++){
            if (((bx + dx) >> 1) != qx) continue;
#pragma unroll
            for (int dy = -1; dy <= 1; dy++){
                if (((by + dy) >> 1) != qy) continue;
#pragma unroll
                for (int dz = -1; dz <= 1; dz++){
                    if (((bz + dz) >> 1) != qz) continue;
                    int t = (dx + 1) * 9 + (dy + 1) * 3 + (dz + 1);
                    sum += W1[(t * C_IN + ci) * 64 + co];
                }
            }
        }
        Wsum1[idx] = f2bf(sum);
    } else if (b < 2480){
        // Wt2 fragment order: idx = (((t*2+kb)*4+nb)*64+l)*8+j
        int idx = (b - 2048) * 256 + tid;
        int j = idx & 7, lq = (idx >> 3) & 63, nb = (idx >> 9) & 3, kb = (idx >> 11) & 1, t = idx >> 12;
        int ci = kb * 32 + (lq >> 4) * 8 + j, co = nb * 16 + (lq & 15);
        Wt2[idx] = f2bf(W2[(t * C_OUT + ci) * 64 + co]);
    } else if (b < 2608){
        int i = (b - 2480) * 256 + tid;
        pg[i] = -1;
        if (b == 2480){
            if (tid < C_IN) h[(size_t)N_PTS * C_IN + tid] = 0;    // zero feature row (conv1)
            if (tid < C_OUT) h2[(size_t)M_PTS * C_OUT + tid] = 0; // zero feature row (conv2)
        }
    } else {
        // gn1 partial: 512 blocks
        __shared__ float ls[64];
        if (tid < 64) ls[tid] = 0.f;
        __syncthreads();
        const int g = tid & 31;
        const int r0 = (b - 2608) * 8 + (tid >> 5);
        float sum = 0.f, sq = 0.f;
        for (int r = r0; r < N_PTS; r += 4096){
            float4 v = *(const float4*)(x + (size_t)r * C_IN + g * 4);
            sum += v.x + v.y + v.z + v.w;
            sq  += v.x*v.x + v.y*v.y + v.z*v.z + v.w*v.w;
        }
        atomicAdd(&ls[g], sum);
        atomicAdd(&ls[32 + g], sq);
        __syncthreads();
        if (tid < 64) atomicAdd(&stats[tid], ls[tid]);
    }
}

// ================= K2: pg_scatter + h_compute + skip =================
// blocks: [0,79) scatter, [79,2579) h (vec4), [2579,7579) skip
__global__ void __launch_bounds__(256) mid_kernel(
    const int* __restrict__ cds, int* __restrict__ pg,
    const float* __restrict__ x, const float* __restrict__ stats,
    const float* __restrict__ g1, const float* __restrict__ b1, ushort* __restrict__ h,
    const float* __restrict__ Wsk, const float* __restrict__ bsk, float* __restrict__ s)
{
    __shared__ float w[C_IN * C_OUT];
    const int b = blockIdx.x, tid = threadIdx.x;
    if (b < 79){
        int i = b * 256 + tid;
        if (i < N_PTS){
            const int* cd = cds + i * 4;
            pg[(cd[1] * 32 + cd[2]) * 32 + cd[3]] = i;
        }
    } else if (b < 2579){
        int i = ((b - 79) * 256 + tid) * 4;
        int c0 = i & (C_IN - 1);
        int g = c0 >> 2;
        float mu = stats[g] * (1.0f / (N_PTS * 4.0f));
        float var = stats[32 + g] * (1.0f / (N_PTS * 4.0f)) - mu * mu;
        float rs = rsqrtf(var + EPS);
        float4 v = *(const float4*)(x + i);
        ushort4 o;
        o.x = f2bf(silu((v.x - mu) * rs * g1[c0+0] + b1[c0+0]));
        o.y = f2bf(silu((v.y - mu) * rs * g1[c0+1] + b1[c0+1]));
        o.z = f2bf(silu((v.z - mu) * rs * g1[c0+2] + b1[c0+2]));
        o.w = f2bf(silu((v.w - mu) * rs * g1[c0+3] + b1[c0+3]));
        *(ushort4*)(h + i) = o;
    } else {
        for (int j = tid; j < C_IN * C_OUT; j += 256) w[j] = Wsk[j];
        __syncthreads();
        int co = tid & 63, pr = tid >> 6;
        int p = (b - 2579) * 4 + pr;
        const float* xr = x + (size_t)p * C_IN;
        float a = bsk[co];
        for (int cb = 0; cb < C_IN; cb += 4){
            float4 v = *(const float4*)(xr + cb);
            a += v.x * w[(cb+0)*64+co] + v.y * w[(cb+1)*64+co]
               + v.z * w[(cb+2)*64+co] + v.w * w[(cb+3)*64+co];
        }
        s[(size_t)p * C_OUT + co] = a;
    }
}

#define MFMA_STAGE(F) \
    acc[0][0] = __builtin_amdgcn_mfma_f32_16x16x32_bf16(F.a0, F.b0, acc[0][0], 0, 0, 0); \
    acc[0][1] = __builtin_amdgcn_mfma_f32_16x16x32_bf16(F.a0, F.b1, acc[0][1], 0, 0, 0); \
    acc[0][2] = __builtin_amdgcn_mfma_f32_16x16x32_bf16(F.a0, F.b2, acc[0][2], 0, 0, 0); \
    acc[0][3] = __builtin_amdgcn_mfma_f32_16x16x32_bf16(F.a0, F.b3, acc[0][3], 0, 0, 0); \
    acc[1][0] = __builtin_amdgcn_mfma_f32_16x16x32_bf16(F.a1, F.b0, acc[1][0], 0, 0, 0); \
    acc[1][1] = __builtin_amdgcn_mfma_f32_16x16x32_bf16(F.a1, F.b1, acc[1][1], 0, 0, 0); \
    acc[1][2] = __builtin_amdgcn_mfma_f32_16x16x32_bf16(F.a1, F.b2, acc[1][2], 0, 0, 0); \
    acc[1][3] = __builtin_amdgcn_mfma_f32_16x16x32_bf16(F.a1, F.b3, acc[1][3], 0, 0, 0);

// ================= conv1: 8-tap parity conv over parents, MFMA, pipelined =================
// grid = 625*8 blocks of 1 wave; block handles 32 parents x parity o -> 32 children rows.
__global__ void __launch_bounds__(64, 4) conv1_parity(
    const ushort* __restrict__ h, const int* __restrict__ pg,
    const int* __restrict__ coords, const ushort* __restrict__ Wsum,
    const float* __restrict__ bias, ushort* __restrict__ hf1_bf,
    float* __restrict__ statsAcc)
{
    __shared__ int rws[8][32];
    const int l = threadIdx.x;
    const int r16 = l & 15, qd = l >> 4;
    const int pb = blockIdx.x >> 3, o = blockIdx.x & 7;
    const int bx = (o >> 2) & 1, by = (o >> 1) & 1, bz = o & 1;

    if (l < 32){
        int p = pb * 32 + l;
        int px = 0, py = 0, pz = 0;
        bool pv = p < N_PTS;
        if (pv){ px = coords[p*4+1]; py = coords[p*4+2]; pz = coords[p*4+3]; }
#pragma unroll
        for (int qi = 0; qi < 8; qi++){
            int nx = px + (bx ? ((qi >> 2) & 1) : ((qi >> 2) & 1) - 1);
            int ny = py + (by ? ((qi >> 1) & 1) : ((qi >> 1) & 1) - 1);
            int nz = pz + (bz ? (qi & 1) : (qi & 1) - 1);
            int row = N_PTS;
            if (pv && (unsigned)nx < 32u && (unsigned)ny < 32u && (unsigned)nz < 32u){
                int pi = pg[(nx * 32 + ny) * 32 + nz];
                if (pi >= 0) row = pi;
            }
            rws[qi][l] = row;
        }
    }
    __syncthreads();

    const ushort* wbase = Wsum + (size_t)o * 65536 + l * 8;
    const int aoff = qd * 8;

    float4v acc[2][4];
#pragma unroll
    for (int i = 0; i < 2; i++)
#pragma unroll
        for (int nb = 0; nb < 4; nb++)
#pragma unroll
            for (int rg = 0; rg < 4; rg++) acc[i][nb][rg] = 0.f;

    auto LD = [&](int s, Frag& f){
        int tap = s >> 2, kb = s & 3;
        int fr0 = rws[tap][r16], fr1 = rws[tap][16 + r16];
        const ushort* a0p = h + (size_t)fr0 * C_IN + aoff + kb * 32;
        const ushort* a1p = h + (size_t)fr1 * C_IN + aoff + kb * 32;
        const ushort* bp = wbase + (tap * 16 + kb * 4) * 512;
        f.a0 = *(const short8*)a0p;
        f.a1 = *(const short8*)a1p;
        f.b0 = *(const short8*)(bp);
        f.b1 = *(const short8*)(bp + 512);
        f.b2 = *(const short8*)(bp + 1024);
        f.b3 = *(const short8*)(bp + 1536);
    };

    Frag f0, f1;
    LD(0, f0); LD(1, f1);
#pragma unroll 2
    for (int s = 0; s < 32; s++){
        Frag nx;
        if (s + 2 < 32) LD(s + 2, nx);
        MFMA_STAGE(f0);
        f0 = f1; f1 = nx;
    }

    // epilogue: C/D row = qd*4+reg (within 16), col = r16; fused GN2 sums
    float bsv[4] = { bias[r16], bias[16 + r16], bias[32 + r16], bias[48 + r16] };
    float ps[4] = {0,0,0,0}, pq[4] = {0,0,0,0};
#pragma unroll
    for (int rb = 0; rb < 2; rb++)
#pragma unroll
        for (int rg = 0; rg < 4; rg++){
            int p = pb * 32 + rb * 16 + qd * 4 + rg;
            if (p < N_PTS){
                size_t base = ((size_t)p * 8 + o) * 64;
#pragma unroll
                for (int nb = 0; nb < 4; nb++){
                    float v = acc[rb][nb][rg] + bsv[nb];
                    hf1_bf[base + nb * 16 + r16] = f2bf(v);
                    ps[nb] += v; pq[nb] += v * v;
                }
            }
        }
#pragma unroll
    for (int nb = 0; nb < 4; nb++){
        float s1 = ps[nb], s2 = pq[nb];
        s1 += __shfl_xor(s1, 16, 64); s2 += __shfl_xor(s2, 16, 64);
        s1 += __shfl_xor(s1, 32, 64); s2 += __shfl_xor(s2, 32, 64);
        if (qd == 0){
            atomicAdd(&statsAcc[64 + nb * 16 + r16], s1);
            atomicAdd(&statsAcc[128 + nb * 16 + r16], s2);
        }
    }
}

// ================= conv2: 27-tap child conv, MFMA, pipelined =================
// grid = 5000 blocks of 1 wave; 32 children per block.
__global__ void __launch_bounds__(64, 4) conv2_direct(
    const ushort* __restrict__ feat, const int* __restrict__ pg,
    const int* __restrict__ coords, const ushort* __restrict__ Wt,
    const float* __restrict__ bias, const float* __restrict__ skip,
    float* __restrict__ out)
{
    __shared__ int rws[27][32];
    const int l = threadIdx.x;
    const int r16 = l & 15, qd = l >> 4;
    const int mb = blockIdx.x * 32;

    if (l < 32){
        int m = mb + l, p = m >> 3, oo = m & 7;
        int cx0 = 2 * coords[p*4+1] + ((oo >> 2) & 1);
        int cy0 = 2 * coords[p*4+2] + ((oo >> 1) & 1);
        int cz0 = 2 * coords[p*4+3] + (oo & 1);
#pragma unroll
        for (int t = 0; t < 27; t++){
            int cx = cx0 + t / 9 - 1, cy = cy0 + (t / 3) % 3 - 1, cz = cz0 + t % 3 - 1;
            int row = M_PTS;
            if ((unsigned)cx < 64u && (unsigned)cy < 64u && (unsigned)cz < 64u){
                int pi = pg[((cx >> 1) * 32 + (cy >> 1)) * 32 + (cz >> 1)];
                if (pi >= 0) row = pi * 8 + (((cx & 1) << 2) | ((cy & 1) << 1) | (cz & 1));
            }
            rws[t][l] = row;
        }
    }
    __syncthreads();

    const ushort* wbase = Wt + l * 8;
    const int aoff = qd * 8;

    float4v acc[2][4];
#pragma unroll
    for (int i = 0; i < 2; i++)
#pragma unroll
        for (int nb = 0; nb < 4; nb++)
#pragma unroll
            for (int rg = 0; rg < 4; rg++) acc[i][nb][rg] = 0.f;

    auto LD = [&](int s, Frag& f){
        int tap = s >> 1, kb = s & 1;
        int fr0 = rws[tap][r16], fr1 = rws[tap][16 + r16];
        const ushort* a0p = feat + (size_t)fr0 * C_OUT + aoff + kb * 32;
        const ushort* a1p = feat + (size_t)fr1 * C_OUT + aoff + kb * 32;
        const ushort* bp = wbase + ((tap * 2 + kb) * 4) * 512;
        f.a0 = *(const short8*)a0p;
        f.a1 = *(const short8*)a1p;
        f.b0 = *(const short8*)(bp);
        f.b1 = *(const short8*)(bp + 512);
        f.b2 = *(const short8*)(bp + 1024);
        f.b3 = *(const short8*)(bp + 1536);
    };

    Frag f0, f1;
    LD(0, f0); LD(1, f1);
#pragma unroll 2
    for (int s = 0; s < 54; s++){
        Frag nx;
        if (s + 2 < 54) LD(s + 2, nx);
        MFMA_STAGE(f0);
        f0 = f1; f1 = nx;
    }

    float bsv[4] = { bias[r16], bias[16 + r16], bias[32 + r16], bias[48 + r16] };
#pragma unroll
    for (int rb = 0; rb < 2; rb++)
#pragma unroll
        for (int rg = 0; rg < 4; rg++){
            int mm = mb + rb * 16 + qd * 4 + rg;
            const float* sk = skip + (size_t)(mm >> 3) * 64;
#pragma unroll
            for (int nb = 0; nb < 4; nb++){
                int co = nb * 16 + r16;
                out[(size_t)mm * 64 + co] = acc[rb][nb][rg] + bsv[nb] + sk[co];
            }
        }
}

// ================= K4: h2 = silu(gn2(hf1_bf16)) -> bf16 =================
__global__ void __launch_bounds__(256) h2_kernel(
    const ushort* __restrict__ hf1, const float* __restrict__ stats,
    const float* __restrict__ gg, const float* __restrict__ gb, ushort* __restrict__ h2)
{
    int i = (blockIdx.x * 256 + threadIdx.x) * 4;
    if (i >= M_PTS * C_OUT) return;
    int c0 = i & (C_OUT - 1);
    const float inv = 1.0f / (M_PTS * 2.0f);
    float muA = (stats[64 + c0] + stats[64 + c0 + 1]) * inv;
    float vA  = (stats[128 + c0] + stats[128 + c0 + 1]) * inv - muA * muA;
    float rsA = rsqrtf(vA + EPS);
    float muB = (stats[64 + c0 + 2] + stats[64 + c0 + 3]) * inv;
    float vB  = (stats[128 + c0 + 2] + stats[128 + c0 + 3]) * inv - muB * muB;
    float rsB = rsqrtf(vB + EPS);
    ushort4 u = *(const ushort4*)(hf1 + i);
    ushort4 o;
    o.x = f2bf(silu((bf2f(u.x) - muA) * rsA * gg[c0+0] + gb[c0+0]));
    o.y = f2bf(silu((bf2f(u.y) - muA) * rsA * gg[c0+1] + gb[c0+1]));
    o.z = f2bf(silu((bf2f(u.z) - muB) * rsB * gg[c0+2] + gb[c0+2]));
    o.w = f2bf(silu((bf2f(u.w) - muB) * rsB * gg[c0+3] + gb[c0+3]));
    *(ushort4*)(h2 + i) = o;
}

extern "C" void kernel_launch(void* const* d_in, const int* in_sizes, int n_in,
                              void* d_out, int out_size, void* d_ws, size_t ws_size,
                              hipStream_t stream){
    const float* x   = (const float*)d_in[0];
    const int*   cds = (const int*)  d_in[1];
    const float* g1  = (const float*)d_in[2];
    const float* b1  = (const float*)d_in[3];
    const float* W1  = (const float*)d_in[4];
    const float* bb1 = (const float*)d_in[5];
    const float* g2  = (const float*)d_in[6];
    const float* b2  = (const float*)d_in[7];
    const float* W2  = (const float*)d_in[8];
    const float* bb2 = (const float*)d_in[9];
    const float* Wsk = (const float*)d_in[10];
    const float* bsk = (const float*)d_in[11];
    float* out = (float*)d_out;
    char* ws = (char*)d_ws;

    // workspace layout (16B-aligned)
    float*  stats = (float*) (ws);                 // 192 f32 (zeroed via memsetAsync)
    int*    pg    = (int*)   (ws + 1024);          // 131072 B -> 132096
    ushort* h     = (ushort*)(ws + 132096);        // (N+1)*128 bf16 -> 5,252,352
    ushort* h2    = (ushort*)(ws + 5252352);       // (M+1)*64 bf16 -> 25,732,480
    float*  s     = (float*) (ws + 25732480);      // N*64 f32 -> 30,852,480
    ushort* Wsum1 = (ushort*)(ws + 30852480);      // 8*8*128*64 bf16 = 1,048,576 -> 31,901,056
    ushort* Wt2   = (ushort*)(ws + 31901056);      // 27*64*64 bf16 = 221,184 -> 32,122,240
    // hf1 (bf16, M*64) lives in d_out between conv1 and h2_kernel; conv2 overwrites d_out as f32.

    hipMemsetAsync(stats, 0, 192 * sizeof(float), stream);
    prep_kernel<<<3120, 256, 0, stream>>>(W1, W2, Wsum1, Wt2, pg, h, h2, x, stats);
    mid_kernel<<<7579, 256, 0, stream>>>(cds, pg, x, stats, g1, b1, h, Wsk, bsk, s);
    conv1_parity<<<625 * 8, 64, 0, stream>>>(h, pg, cds, Wsum1, bb1, (ushort*)d_out, stats);
    h2_kernel<<<12500, 256, 0, stream>>>((const ushort*)d_out, stats, g2, b2, h2);
    conv2_direct<<<5000, 64, 0, stream>>>(h2, pg, cds, Wt2, bb2, s, out);
}

// Round 8
// 481.354 us; speedup vs baseline: 1.0475x; 1.0475x over previous
//
#include <hip/hip_runtime.h>
#include <hip/hip_bf16.h>
#include <math.h>

#define N_PTS 20000
#define C_IN 128
#define C_OUT 64
#define M_PTS (N_PTS*8)
#define EPS 1e-5f

typedef __attribute__((ext_vector_type(8))) short short8;
typedef __attribute__((ext_vector_type(4))) float float4v;

__device__ __forceinline__ ushort f2bf(float f){
    unsigned int i = __float_as_uint(f);
    unsigned int r = i + 0x7fffu + ((i >> 16) & 1u);
    return (ushort)(r >> 16);
}
__device__ __forceinline__ float bf2f(ushort u){ return __uint_as_float(((unsigned int)u) << 16); }
__device__ __forceinline__ float silu(float z){ return z / (1.f + expf(-z)); }

struct Frag { short8 a0, a1, b0, b1, b2, b3; };

// stats layout (fp32, ws): [0..31] gn1 group sum, [32..63] gn1 group sumsq,
//                          [64..127] gn2 ch sum, [128..191] gn2 ch sumsq

// ================= K1: Wsum1 prep + Wt2 prep + pg_init + gn1_partial =================
// blocks: [0,2048) Wsum1, [2048,2480) Wt2, [2480,2608) pg_init, [2608,3120) gn1
__global__ void __launch_bounds__(256) prep_kernel(
    const float* __restrict__ W1, const float* __restrict__ W2,
    ushort* __restrict__ Wsum1, ushort* __restrict__ Wt2,
    int* __restrict__ pg, ushort* __restrict__ h, ushort* __restrict__ h2,
    const float* __restrict__ x, float* __restrict__ stats)
{
    const int b = blockIdx.x, tid = threadIdx.x;
    if (b < 2048){
        // Wsum1[(((o*8+qi)*4+kb)*4+nb)*512 + l*8 + j] = sum of W1 taps mapping to parent-offset q
        int idx = b * 256 + tid;
        int j = idx & 7, lq = (idx >> 3) & 63, nb = (idx >> 9) & 3, kb = (idx >> 11) & 3, tq = idx >> 13;
        int o = tq >> 3, qi = tq & 7;
        int bx = (o >> 2) & 1, by = (o >> 1) & 1, bz = o & 1;
        int qx = (bx ? ((qi >> 2) & 1) : ((qi >> 2) & 1) - 1);
        int qy = (by ? ((qi >> 1) & 1) : ((qi >> 1) & 1) - 1);
        int qz = (bz ? (qi & 1) : (qi & 1) - 1);
        int ci = kb * 32 + (lq >> 4) * 8 + j, co = nb * 16 + (lq & 15);
        float sum = 0.f;
#pragma unroll
        for (int dx = -1; dx <= 1; dx++){
            if (((bx + dx) >> 1) != qx) continue;
#pragma unroll
            for (int dy = -1; dy <= 1; dy++){
                if (((by + dy) >> 1) != qy) continue;
#pragma unroll
                for (int dz = -1; dz <= 1; dz++){
                    if (((bz + dz) >> 1) != qz) continue;
                    int t = (dx + 1) * 9 + (dy + 1) * 3 + (dz + 1);
                    sum += W1[(t * C_IN + ci) * 64 + co];
                }
            }
        }
        Wsum1[idx] = f2bf(sum);
    } else if (b < 2480){
        // Wt2 fragment order: idx = (((t*2+kb)*4+nb)*64+l)*8+j
        int idx = (b - 2048) * 256 + tid;
        int j = idx & 7, lq = (idx >> 3) & 63, nb = (idx >> 9) & 3, kb = (idx >> 11) & 1, t = idx >> 12;
        int ci = kb * 32 + (lq >> 4) * 8 + j, co = nb * 16 + (lq & 15);
        Wt2[idx] = f2bf(W2[(t * C_OUT + ci) * 64 + co]);
    } else if (b < 2608){
        int i = (b - 2480) * 256 + tid;
        pg[i] = -1;
        if (b == 2480){
            if (tid < C_IN) h[(size_t)N_PTS * C_IN + tid] = 0;    // zero feature row (conv1)
            if (tid < C_OUT) h2[(size_t)M_PTS * C_OUT + tid] = 0; // zero feature row (conv2)
        }
    } else {
        // gn1 partial: 512 blocks
        __shared__ float ls[64];
        if (tid < 64) ls[tid] = 0.f;
        __syncthreads();
        const int g = tid & 31;
        const int r0 = (b - 2608) * 8 + (tid >> 5);
        float sum = 0.f, sq = 0.f;
        for (int r = r0; r < N_PTS; r += 4096){
            float4 v = *(const float4*)(x + (size_t)r * C_IN + g * 4);
            sum += v.x + v.y + v.z + v.w;
            sq  += v.x*v.x + v.y*v.y + v.z*v.z + v.w*v.w;
        }
        atomicAdd(&ls[g], sum);
        atomicAdd(&ls[32 + g], sq);
        __syncthreads();
        if (tid < 64) atomicAdd(&stats[tid], ls[tid]);
    }
}

// ================= K2: pg_scatter + h_compute + skip =================
// blocks: [0,79) scatter, [79,2579) h (vec4), [2579,7579) skip
__global__ void __launch_bounds__(256) mid_kernel(
    const int* __restrict__ cds, int* __restrict__ pg,
    const float* __restrict__ x, const float* __restrict__ stats,
    const float* __restrict__ g1, const float* __restrict__ b1, ushort* __restrict__ h,
    const float* __restrict__ Wsk, const float* __restrict__ bsk, float* __restrict__ s)
{
    __shared__ float w[C_IN * C_OUT];
    const int b = blockIdx.x, tid = threadIdx.x;
    if (b < 79){
        int i = b * 256 + tid;
        if (i < N_PTS){
            const int* cd = cds + i * 4;
            pg[(cd[1] * 32 + cd[2]) * 32 + cd[3]] = i;
        }
    } else if (b < 2579){
        int i = ((b - 79) * 256 + tid) * 4;
        int c0 = i & (C_IN - 1);
        int g = c0 >> 2;
        float mu = stats[g] * (1.0f / (N_PTS * 4.0f));
        float var = stats[32 + g] * (1.0f / (N_PTS * 4.0f)) - mu * mu;
        float rs = rsqrtf(var + EPS);
        float4 v = *(const float4*)(x + i);
        ushort4 o;
        o.x = f2bf(silu((v.x - mu) * rs * g1[c0+0] + b1[c0+0]));
        o.y = f2bf(silu((v.y - mu) * rs * g1[c0+1] + b1[c0+1]));
        o.z = f2bf(silu((v.z - mu) * rs * g1[c0+2] + b1[c0+2]));
        o.w = f2bf(silu((v.w - mu) * rs * g1[c0+3] + b1[c0+3]));
        *(ushort4*)(h + i) = o;
    } else {
        for (int j = tid; j < C_IN * C_OUT; j += 256) w[j] = Wsk[j];
        __syncthreads();
        int co = tid & 63, pr = tid >> 6;
        int p = (b - 2579) * 4 + pr;
        const float* xr = x + (size_t)p * C_IN;
        float a = bsk[co];
        for (int cb = 0; cb < C_IN; cb += 4){
            float4 v = *(const float4*)(xr + cb);
            a += v.x * w[(cb+0)*64+co] + v.y * w[(cb+1)*64+co]
               + v.z * w[(cb+2)*64+co] + v.w * w[(cb+3)*64+co];
        }
        s[(size_t)p * C_OUT + co] = a;
    }
}

#define MFMA_STAGE(F) \
    acc[0][0] = __builtin_amdgcn_mfma_f32_16x16x32_bf16(F.a0, F.b0, acc[0][0], 0, 0, 0); \
    acc[0][1] = __builtin_amdgcn_mfma_f32_16x16x32_bf16(F.a0, F.b1, acc[0][1], 0, 0, 0); \
    acc[0][2] = __builtin_amdgcn_mfma_f32_16x16x32_bf16(F.a0, F.b2, acc[0][2], 0, 0, 0); \
    acc[0][3] = __builtin_amdgcn_mfma_f32_16x16x32_bf16(F.a0, F.b3, acc[0][3], 0, 0, 0); \
    acc[1][0] = __builtin_amdgcn_mfma_f32_16x16x32_bf16(F.a1, F.b0, acc[1][0], 0, 0, 0); \
    acc[1][1] = __builtin_amdgcn_mfma_f32_16x16x32_bf16(F.a1, F.b1, acc[1][1], 0, 0, 0); \
    acc[1][2] = __builtin_amdgcn_mfma_f32_16x16x32_bf16(F.a1, F.b2, acc[1][2], 0, 0, 0); \
    acc[1][3] = __builtin_amdgcn_mfma_f32_16x16x32_bf16(F.a1, F.b3, acc[1][3], 0, 0, 0);

// ================= conv1: 8-tap parity conv over parents, 4-wave blocks =================
// grid = 625*2; block = 32 parents x 4 parities (wave w -> parity (blk&1)*4+w), M=32/wave.
__global__ void __launch_bounds__(256, 4) conv1_parity(
    const ushort* __restrict__ h, const int* __restrict__ pg,
    const int* __restrict__ coords, const ushort* __restrict__ Wsum,
    const float* __restrict__ bias, ushort* __restrict__ hf1_bf,
    float* __restrict__ statsAcc)
{
    __shared__ int nbr[27 * 32];
    __shared__ ushort ep[4][32 * 64];
    const int tid = threadIdx.x;
    const int l = tid & 63, w = tid >> 6;
    const int r16 = l & 15, qd = l >> 4;
    const int pb = blockIdx.x >> 1;
    const int o = ((blockIdx.x & 1) << 2) | w;
    const int bx = (o >> 2) & 1, by = (o >> 1) & 1, bz = o & 1;

    // 27-neighborhood parent rows for the block's 32 parents (864 entries, cooperative)
    for (int e = tid; e < 27 * 32; e += 256){
        int t = e >> 5, pi = e & 31;
        const int* cd = coords + (pb * 32 + pi) * 4;
        int nx = cd[1] + t / 9 - 1, ny = cd[2] + (t / 3) % 3 - 1, nz = cd[3] + t % 3 - 1;
        int row = N_PTS;
        if ((unsigned)nx < 32u && (unsigned)ny < 32u && (unsigned)nz < 32u){
            int pi2 = pg[(nx * 32 + ny) * 32 + nz];
            if (pi2 >= 0) row = pi2;
        }
        nbr[e] = row;
    }
    __syncthreads();

    // preload this wave's 8 tap-row pairs into registers
    int fra[8], frb[8];
#pragma unroll
    for (int qi = 0; qi < 8; qi++){
        int t = (((qi >> 2) & 1) + bx) * 9 + (((qi >> 1) & 1) + by) * 3 + ((qi & 1) + bz);
        fra[qi] = nbr[t * 32 + r16];
        frb[qi] = nbr[t * 32 + 16 + r16];
    }

    const ushort* wbase = Wsum + (size_t)o * 65536 + l * 8;
    const int aoff = qd * 8;

    float4v acc[2][4];
#pragma unroll
    for (int i = 0; i < 2; i++)
#pragma unroll
        for (int nb = 0; nb < 4; nb++)
#pragma unroll
            for (int rg = 0; rg < 4; rg++) acc[i][nb][rg] = 0.f;

    auto LD = [&](int s, Frag& f){
        int qi = s >> 2, kb = s & 3;
        const ushort* a0p = h + (size_t)fra[qi] * C_IN + aoff + kb * 32;
        const ushort* a1p = h + (size_t)frb[qi] * C_IN + aoff + kb * 32;
        const ushort* bp = wbase + (qi * 16 + kb * 4) * 512;
        f.a0 = *(const short8*)a0p;
        f.a1 = *(const short8*)a1p;
        f.b0 = *(const short8*)(bp);
        f.b1 = *(const short8*)(bp + 512);
        f.b2 = *(const short8*)(bp + 1024);
        f.b3 = *(const short8*)(bp + 1536);
    };

    Frag f0, f1;
    LD(0, f0); LD(1, f1);
#pragma unroll
    for (int s = 0; s < 32; s++){
        Frag nx;
        if (s + 2 < 32) LD(s + 2, nx);
        MFMA_STAGE(f0);
        f0 = f1; f1 = nx;
    }

    // epilogue: bias + f2bf + stats, staged through per-wave LDS, coalesced store
    float bsv[4] = { bias[r16], bias[16 + r16], bias[32 + r16], bias[48 + r16] };
    float ps[4] = {0,0,0,0}, pq[4] = {0,0,0,0};
#pragma unroll
    for (int rb = 0; rb < 2; rb++)
#pragma unroll
        for (int rg = 0; rg < 4; rg++){
            int rloc = rb * 16 + qd * 4 + rg;
#pragma unroll
            for (int nb = 0; nb < 4; nb++){
                float v = acc[rb][nb][rg] + bsv[nb];
                ep[w][rloc * 64 + nb * 16 + r16] = f2bf(v);
                ps[nb] += v; pq[nb] += v * v;
            }
        }
#pragma unroll
    for (int pass = 0; pass < 4; pass++){
        int c = pass * 64 + l;              // 256 chunks: 32 rows x 8 x 16B
        int rloc = c >> 3, off = (c & 7) * 8;
        size_t p = pb * 32 + rloc;
        *(uint4*)(hf1_bf + (p * 8 + o) * 64 + off) = *(const uint4*)(ep[w] + rloc * 64 + off);
    }
#pragma unroll
    for (int nb = 0; nb < 4; nb++){
        float s1 = ps[nb], s2 = pq[nb];
        s1 += __shfl_xor(s1, 16, 64); s2 += __shfl_xor(s2, 16, 64);
        s1 += __shfl_xor(s1, 32, 64); s2 += __shfl_xor(s2, 32, 64);
        if (qd == 0){
            atomicAdd(&statsAcc[64 + nb * 16 + r16], s1);
            atomicAdd(&statsAcc[128 + nb * 16 + r16], s2);
        }
    }
}

// ================= conv2: 27-tap child conv, 4-wave blocks =================
// grid = 1250; block = 128 children, wave w handles rows [w*32, w*32+32).
__global__ void __launch_bounds__(256, 4) conv2_direct(
    const ushort* __restrict__ feat, const int* __restrict__ pg,
    const int* __restrict__ coords, const ushort* __restrict__ Wt,
    const float* __restrict__ bias, const float* __restrict__ skip,
    float* __restrict__ out)
{
    __shared__ char shbuf[32768];            // union: rws (13.8 KB) then epilogue (32 KB)
    int* rws = (int*)shbuf;                  // rws[t*128 + ml]
    const int tid = threadIdx.x;
    const int l = tid & 63, w = tid >> 6;
    const int r16 = l & 15, qd = l >> 4;
    const int mb = blockIdx.x * 128;
    const int wm = w * 32;

    if (tid < 128){
        int m = mb + tid, p = m >> 3, oo = m & 7;
        int cx0 = 2 * coords[p*4+1] + ((oo >> 2) & 1);
        int cy0 = 2 * coords[p*4+2] + ((oo >> 1) & 1);
        int cz0 = 2 * coords[p*4+3] + (oo & 1);
#pragma unroll
        for (int t = 0; t < 27; t++){
            int cx = cx0 + t / 9 - 1, cy = cy0 + (t / 3) % 3 - 1, cz = cz0 + t % 3 - 1;
            int row = M_PTS;
            if ((unsigned)cx < 64u && (unsigned)cy < 64u && (unsigned)cz < 64u){
                int pi = pg[((cx >> 1) * 32 + (cy >> 1)) * 32 + (cz >> 1)];
                if (pi >= 0) row = pi * 8 + (((cx & 1) << 2) | ((cy & 1) << 1) | (cz & 1));
            }
            rws[t * 128 + tid] = row;
        }
    }
    __syncthreads();

    const ushort* wbase = Wt + l * 8;
    const int aoff = qd * 8;

    float4v acc[2][4];
#pragma unroll
    for (int i = 0; i < 2; i++)
#pragma unroll
        for (int nb = 0; nb < 4; nb++)
#pragma unroll
            for (int rg = 0; rg < 4; rg++) acc[i][nb][rg] = 0.f;

    auto LD = [&](int s, Frag& f){
        int tap = s >> 1, kb = s & 1;
        int fr0 = rws[tap * 128 + wm + r16], fr1 = rws[tap * 128 + wm + 16 + r16];
        const ushort* a0p = feat + (size_t)fr0 * C_OUT + aoff + kb * 32;
        const ushort* a1p = feat + (size_t)fr1 * C_OUT + aoff + kb * 32;
        const ushort* bp = wbase + ((tap * 2 + kb) * 4) * 512;
        f.a0 = *(const short8*)a0p;
        f.a1 = *(const short8*)a1p;
        f.b0 = *(const short8*)(bp);
        f.b1 = *(const short8*)(bp + 512);
        f.b2 = *(const short8*)(bp + 1024);
        f.b3 = *(const short8*)(bp + 1536);
    };

    Frag f0, f1;
    LD(0, f0); LD(1, f1);
#pragma unroll 2
    for (int s = 0; s < 54; s++){
        Frag nx;
        if (s + 2 < 54) LD(s + 2, nx);
        MFMA_STAGE(f0);
        f0 = f1; f1 = nx;
    }

    // epilogue: stage fp32 tile in LDS (reuses rws space), coalesced float4 store + skip
    __syncthreads();                          // all waves past the loop before overwriting rws
    float* myep = (float*)shbuf + w * 2048;   // 32 x 64 f32
    float bsv[4] = { bias[r16], bias[16 + r16], bias[32 + r16], bias[48 + r16] };
#pragma unroll
    for (int rb = 0; rb < 2; rb++)
#pragma unroll
        for (int rg = 0; rg < 4; rg++){
            int rloc = rb * 16 + qd * 4 + rg;
#pragma unroll
            for (int nb = 0; nb < 4; nb++)
                myep[rloc * 64 + nb * 16 + r16] = acc[rb][nb][rg] + bsv[nb];
        }
#pragma unroll
    for (int pass = 0; pass < 8; pass++){
        int c = pass * 64 + l;                // 512 chunks: 32 rows x 16 x 16B
        int rloc = c >> 4, coff = (c & 15) * 4;
        int mm = mb + wm + rloc;
        float4 v = *(const float4*)(myep + rloc * 64 + coff);
        float4 sk = *(const float4*)(skip + (size_t)(mm >> 3) * 64 + coff);
        v.x += sk.x; v.y += sk.y; v.z += sk.z; v.w += sk.w;
        *(float4*)(out + (size_t)mm * 64 + coff) = v;
    }
}

// ================= K4: h2 = silu(gn2(hf1_bf16)) -> bf16 =================
__global__ void __launch_bounds__(256) h2_kernel(
    const ushort* __restrict__ hf1, const float* __restrict__ stats,
    const float* __restrict__ gg, const float* __restrict__ gb, ushort* __restrict__ h2)
{
    int i = (blockIdx.x * 256 + threadIdx.x) * 4;
    if (i >= M_PTS * C_OUT) return;
    int c0 = i & (C_OUT - 1);
    const float inv = 1.0f / (M_PTS * 2.0f);
    float muA = (stats[64 + c0] + stats[64 + c0 + 1]) * inv;
    float vA  = (stats[128 + c0] + stats[128 + c0 + 1]) * inv - muA * muA;
    float rsA = rsqrtf(vA + EPS);
    float muB = (stats[64 + c0 + 2] + stats[64 + c0 + 3]) * inv;
    float vB  = (stats[128 + c0 + 2] + stats[128 + c0 + 3]) * inv - muB * muB;
    float rsB = rsqrtf(vB + EPS);
    ushort4 u = *(const ushort4*)(hf1 + i);
    ushort4 o;
    o.x = f2bf(silu((bf2f(u.x) - muA) * rsA * gg[c0+0] + gb[c0+0]));
    o.y = f2bf(silu((bf2f(u.y) - muA) * rsA * gg[c0+1] + gb[c0+1]));
    o.z = f2bf(silu((bf2f(u.z) - muB) * rsB * gg[c0+2] + gb[c0+2]));
    o.w = f2bf(silu((bf2f(u.w) - muB) * rsB * gg[c0+3] + gb[c0+3]));
    *(ushort4*)(h2 + i) = o;
}

extern "C" void kernel_launch(void* const* d_in, const int* in_sizes, int n_in,
                              void* d_out, int out_size, void* d_ws, size_t ws_size,
                              hipStream_t stream){
    const float* x   = (const float*)d_in[0];
    const int*   cds = (const int*)  d_in[1];
    const float* g1  = (const float*)d_in[2];
    const float* b1  = (const float*)d_in[3];
    const float* W1  = (const float*)d_in[4];
    const float* bb1 = (const float*)d_in[5];
    const float* g2  = (const float*)d_in[6];
    const float* b2  = (const float*)d_in[7];
    const float* W2  = (const float*)d_in[8];
    const float* bb2 = (const float*)d_in[9];
    const float* Wsk = (const float*)d_in[10];
    const float* bsk = (const float*)d_in[11];
    float* out = (float*)d_out;
    char* ws = (char*)d_ws;

    // workspace layout (16B-aligned)
    float*  stats = (float*) (ws);                 // 192 f32 (zeroed via memsetAsync)
    int*    pg    = (int*)   (ws + 1024);          // 131072 B -> 132096
    ushort* h     = (ushort*)(ws + 132096);        // (N+1)*128 bf16 -> 5,252,352
    ushort* h2    = (ushort*)(ws + 5252352);       // (M+1)*64 bf16 -> 25,732,480
    float*  s     = (float*) (ws + 25732480);      // N*64 f32 -> 30,852,480
    ushort* Wsum1 = (ushort*)(ws + 30852480);      // 8*8*128*64 bf16 = 1,048,576 -> 31,901,056
    ushort* Wt2   = (ushort*)(ws + 31901056);      // 27*64*64 bf16 = 221,184 -> 32,122,240
    // hf1 (bf16, M*64) lives in d_out between conv1 and h2_kernel; conv2 overwrites d_out as f32.

    hipMemsetAsync(stats, 0, 192 * sizeof(float), stream);
    prep_kernel<<<3120, 256, 0, stream>>>(W1, W2, Wsum1, Wt2, pg, h, h2, x, stats);
    mid_kernel<<<7579, 256, 0, stream>>>(cds, pg, x, stats, g1, b1, h, Wsk, bsk, s);
    conv1_parity<<<1250, 256, 0, stream>>>(h, pg, cds, Wsum1, bb1, (ushort*)d_out, stats);
    h2_kernel<<<12500, 256, 0, stream>>>((const ushort*)d_out, stats, g2, b2, h2);
    conv2_direct<<<1250, 256, 0, stream>>>(h2, pg, cds, Wt2, bb2, s, out);
}